// Round 1
// baseline (548.966 us; speedup 1.0000x reference)
//
#include <hip/hip_runtime.h>
#include <hip/hip_bf16.h>
#include <math.h>

#define ALPHA 0.3f
#define K_NB 32
#define C_DIM 64
#define H_DIM 64
#define WAVES_PER_BLOCK 4

__device__ __forceinline__ float leaky(float x) {
    return x >= 0.0f ? x : ALPHA * x;
}

// Stage 1: hq[n][h] = leaky_relu(sum_c embs[n][c] * Qw[c][h] + Qb[h])
// One wave per node, lane = h.
__global__ void stage1_kernel(const float* __restrict__ embs,
                              const float* __restrict__ Qw,
                              const float* __restrict__ Qb,
                              float* __restrict__ hq,
                              int N) {
    __shared__ float s_Qw[C_DIM * H_DIM];   // 16 KB
    int tid = threadIdx.x;
    for (int i = tid; i < C_DIM * H_DIM; i += blockDim.x)
        s_Qw[i] = Qw[i];
    __syncthreads();

    int wave = tid >> 6;
    int lane = tid & 63;
    int n = blockIdx.x * WAVES_PER_BLOCK + wave;
    if (n >= N) return;

    const float* e = embs + (size_t)n * C_DIM;
    float acc = Qb[lane];
    #pragma unroll
    for (int c = 0; c < C_DIM; ++c)
        acc += e[c] * s_Qw[c * H_DIM + lane];   // e[c] wave-uniform broadcast
    hq[(size_t)n * H_DIM + lane] = leaky(acc);
}

// Stage 2: per node:
//   sw  = sum_k weights[n, nb_k]
//   ws[h] = (sum_k weights[n, nb_k] * hq[nb_k][h]) / (sw + 1e-6)
//   concat = [embs[n] (64) , ws (64)]
//   o[h] = leaky_relu(sum_{c<128} concat[c]*Ww[c][h] + Wb[h])
//   out[n][h] = o[h] / (||o|| + 1e-6)
// One wave per node, lane = h.
__global__ void stage2_kernel(const float* __restrict__ embs,
                              const float* __restrict__ weights,
                              const int*   __restrict__ nbset,
                              const float* __restrict__ Ww,
                              const float* __restrict__ Wb,
                              const float* __restrict__ hq,
                              float* __restrict__ out,
                              int N) {
    __shared__ float s_Ww[(C_DIM + H_DIM) * H_DIM];       // 128*64*4 = 32 KB
    __shared__ float s_concat[WAVES_PER_BLOCK][C_DIM + H_DIM]; // 2 KB

    int tid = threadIdx.x;
    for (int i = tid; i < (C_DIM + H_DIM) * H_DIM; i += blockDim.x)
        s_Ww[i] = Ww[i];

    int wave = tid >> 6;
    int lane = tid & 63;
    int n = blockIdx.x * WAVES_PER_BLOCK + wave;

    if (n < N) {
        const int* nb_row = nbset + (size_t)n * K_NB;
        const float* w_row = weights + (size_t)n * (size_t)N;

        float acc = 0.0f;
        float sw  = 0.0f;
        #pragma unroll
        for (int k = 0; k < K_NB; ++k) {
            int nb = nb_row[k];                       // wave-uniform
            float w = w_row[nb];                      // wave-uniform broadcast load
            acc += w * hq[(size_t)nb * H_DIM + lane]; // coalesced 256 B row
            sw  += w;
        }
        float ws = acc / (sw + 1e-6f);
        s_concat[wave][lane]          = embs[(size_t)n * C_DIM + lane];
        s_concat[wave][C_DIM + lane]  = ws;
    }
    __syncthreads();

    if (n < N) {
        float o = Wb[lane];
        #pragma unroll
        for (int c = 0; c < C_DIM + H_DIM; ++c)
            o += s_concat[wave][c] * s_Ww[c * H_DIM + lane];
        o = leaky(o);

        // wave-wide sum of squares (64 lanes)
        float sq = o * o;
        #pragma unroll
        for (int off = 32; off > 0; off >>= 1)
            sq += __shfl_xor(sq, off, 64);

        out[(size_t)n * H_DIM + lane] = o / (sqrtf(sq) + 1e-6f);
    }
}

extern "C" void kernel_launch(void* const* d_in, const int* in_sizes, int n_in,
                              void* d_out, int out_size, void* d_ws, size_t ws_size,
                              hipStream_t stream) {
    const float* embs    = (const float*)d_in[0];   // (1, N, 64)
    const float* weights = (const float*)d_in[1];   // (N, N)
    const int*   nbset   = (const int*)  d_in[2];   // (N, 32)
    const float* Qw      = (const float*)d_in[3];   // (64, 64)
    const float* Qb      = (const float*)d_in[4];   // (64,)
    const float* Ww      = (const float*)d_in[5];   // (128, 64)
    const float* Wb      = (const float*)d_in[6];   // (64,)
    float* out = (float*)d_out;                     // (1, N, 64)

    const int N = in_sizes[2] / K_NB;               // 10000

    float* hq = (float*)d_ws;                       // N*64 floats = 2.56 MB

    int blocks = (N + WAVES_PER_BLOCK - 1) / WAVES_PER_BLOCK;
    stage1_kernel<<<blocks, WAVES_PER_BLOCK * 64, 0, stream>>>(embs, Qw, Qb, hq, N);
    stage2_kernel<<<blocks, WAVES_PER_BLOCK * 64, 0, stream>>>(embs, weights, nbset,
                                                               Ww, Wb, hq, out, N);
}

// Round 2
// 467.515 us; speedup vs baseline: 1.1742x; 1.1742x over previous
//
#include <hip/hip_runtime.h>
#include <hip/hip_bf16.h>
#include <math.h>

#define ALPHA 0.3f
#define K_NB  32
#define C_DIM 64
#define H_DIM 64
#define WPB   4   // waves per block

__device__ __forceinline__ float leaky(float x) { return x >= 0.0f ? x : ALPHA * x; }

// Broadcast lane l's value to all lanes via v_readlane (VALU pipe, no LDS).
__device__ __forceinline__ float lane_bcast(float v, int l) {
    return __uint_as_float(__builtin_amdgcn_readlane(__float_as_uint(v), l));
}

// Stage 1: hq[n][h] = leaky_relu(embs[n] @ Qw + Qb), one wave per node, lane = h.
__global__ void __launch_bounds__(256) stage1_kernel(
        const float* __restrict__ embs, const float* __restrict__ Qw,
        const float* __restrict__ Qb, float* __restrict__ hq, int N) {
    __shared__ float s_Qw[C_DIM * H_DIM];          // 16 KB
    int tid = threadIdx.x;
    const float4* q4 = (const float4*)Qw;
    float4* s4 = (float4*)s_Qw;
    for (int i = tid; i < C_DIM * H_DIM / 4; i += blockDim.x) s4[i] = q4[i];
    __syncthreads();

    int wave = tid >> 6, lane = tid & 63;
    int n = blockIdx.x * WPB + wave;
    if (n >= N) return;

    float e = embs[(size_t)n * C_DIM + lane];      // own element only
    float a0 = Qb[lane], a1 = 0.0f;
    #pragma unroll
    for (int c = 0; c < C_DIM; c += 2) {
        a0 = fmaf(lane_bcast(e, c),     s_Qw[c * H_DIM + lane],       a0);
        a1 = fmaf(lane_bcast(e, c + 1), s_Qw[(c + 1) * H_DIM + lane], a1);
    }
    hq[(size_t)n * H_DIM + lane] = leaky(a0 + a1);
}

// Stage 2: weighted neighbor-average of hq, concat with embs, 128->64 linear,
// leaky_relu, L2 normalize. One wave per node, lane = h.
__global__ void __launch_bounds__(256) stage2_kernel(
        const float* __restrict__ embs, const float* __restrict__ weights,
        const int*   __restrict__ nbset, const float* __restrict__ Ww,
        const float* __restrict__ Wb, const float* __restrict__ hq,
        float* __restrict__ out, int N) {
    __shared__ float s_Ww[(C_DIM + H_DIM) * H_DIM];   // 32 KB
    int tid = threadIdx.x;
    const float4* w4 = (const float4*)Ww;
    float4* s4 = (float4*)s_Ww;
    for (int i = tid; i < (C_DIM + H_DIM) * H_DIM / 4; i += blockDim.x) s4[i] = w4[i];
    __syncthreads();

    int wave = tid >> 6, lane = tid & 63;
    int n = blockIdx.x * WPB + wave;
    if (n >= N) return;

    // Lane k holds nb[k] (lanes 32..63 duplicate); readlane -> SGPR -> scalar gather.
    const int* nb_row = nbset + (size_t)n * K_NB;
    int my_nb = nb_row[lane & (K_NB - 1)];
    const float* w_row = weights + (size_t)n * (size_t)N;

    float acc = 0.0f, sw = 0.0f;
    #pragma unroll
    for (int k = 0; k < K_NB; ++k) {
        int nb = __builtin_amdgcn_readlane(my_nb, k);      // wave-uniform SGPR
        float w = w_row[nb];                               // uniform (scalar) load
        acc = fmaf(w, hq[(size_t)nb * H_DIM + lane], acc); // coalesced 256 B row
        sw += w;
    }
    float ws = acc / (sw + 1e-6f);
    float e  = embs[(size_t)n * C_DIM + lane];

    float o0 = Wb[lane], o1 = 0.0f;
    #pragma unroll
    for (int c = 0; c < C_DIM; c += 2) {
        o0 = fmaf(lane_bcast(e, c),     s_Ww[c * H_DIM + lane],       o0);
        o1 = fmaf(lane_bcast(e, c + 1), s_Ww[(c + 1) * H_DIM + lane], o1);
    }
    #pragma unroll
    for (int c = 0; c < C_DIM; c += 2) {
        o0 = fmaf(lane_bcast(ws, c),     s_Ww[(C_DIM + c) * H_DIM + lane],     o0);
        o1 = fmaf(lane_bcast(ws, c + 1), s_Ww[(C_DIM + c + 1) * H_DIM + lane], o1);
    }
    float o = leaky(o0 + o1);

    float sq = o * o;
    #pragma unroll
    for (int off = 32; off > 0; off >>= 1) sq += __shfl_xor(sq, off, 64);
    out[(size_t)n * H_DIM + lane] = o / (sqrtf(sq) + 1e-6f);
}

extern "C" void kernel_launch(void* const* d_in, const int* in_sizes, int n_in,
                              void* d_out, int out_size, void* d_ws, size_t ws_size,
                              hipStream_t stream) {
    const float* embs    = (const float*)d_in[0];   // (1, N, 64)
    const float* weights = (const float*)d_in[1];   // (N, N)
    const int*   nbset   = (const int*)  d_in[2];   // (N, 32)
    const float* Qw      = (const float*)d_in[3];   // (64, 64)
    const float* Qb      = (const float*)d_in[4];   // (64,)
    const float* Ww      = (const float*)d_in[5];   // (128, 64)
    const float* Wb      = (const float*)d_in[6];   // (64,)
    float* out = (float*)d_out;                     // (1, N, 64)

    const int N = in_sizes[2] / K_NB;               // 10000
    float* hq = (float*)d_ws;                       // N*64 floats = 2.56 MB

    int blocks = (N + WPB - 1) / WPB;
    stage1_kernel<<<blocks, WPB * 64, 0, stream>>>(embs, Qw, Qb, hq, N);
    stage2_kernel<<<blocks, WPB * 64, 0, stream>>>(embs, weights, nbset,
                                                   Ww, Wb, hq, out, N);
}

// Round 3
// 462.069 us; speedup vs baseline: 1.1881x; 1.0118x over previous
//
#include <hip/hip_runtime.h>
#include <hip/hip_bf16.h>
#include <math.h>

#define ALPHA 0.3f
#define K_NB  32
#define C_DIM 64
#define H_DIM 64
#define WPB   8   // waves per block (512 threads); 10000/8 = 1250 blocks exactly

__device__ __forceinline__ float leaky(float x) { return x >= 0.0f ? x : ALPHA * x; }

__device__ __forceinline__ float lane_bcast(float v, int l) {
    return __uint_as_float(__builtin_amdgcn_readlane(__float_as_uint(v), l));
}

// Stage 1: hq[n][h] = leaky_relu(embs[n] @ Qw + Qb), one wave per node, lane = h.
__global__ void __launch_bounds__(WPB * 64) stage1_kernel(
        const float* __restrict__ embs, const float* __restrict__ Qw,
        const float* __restrict__ Qb, float* __restrict__ hq, int N) {
    __shared__ float s_Qw[C_DIM * H_DIM];          // 16 KB
    int tid = threadIdx.x;
    const float4* q4 = (const float4*)Qw;
    float4* s4 = (float4*)s_Qw;
    for (int i = tid; i < C_DIM * H_DIM / 4; i += blockDim.x) s4[i] = q4[i];
    __syncthreads();

    int wave = tid >> 6, lane = tid & 63;
    int n = blockIdx.x * WPB + wave;
    if (n >= N) return;

    float e = embs[(size_t)n * C_DIM + lane];      // own element only
    float a0 = Qb[lane], a1 = 0.0f;
    #pragma unroll
    for (int c = 0; c < C_DIM; c += 2) {
        float w0 = s_Qw[c * H_DIM + lane];         // adjacent pair -> ds_read2_b32
        float w1 = s_Qw[(c + 1) * H_DIM + lane];
        a0 = fmaf(lane_bcast(e, c),     w0, a0);
        a1 = fmaf(lane_bcast(e, c + 1), w1, a1);
    }
    hq[(size_t)n * H_DIM + lane] = leaky(a0 + a1);
}

// Stage 2: weighted neighbor-average of hq, concat with embs, 128->64 linear,
// leaky_relu, L2 normalize. One wave per node, lane = h.
__global__ void __launch_bounds__(WPB * 64) stage2_kernel(
        const float* __restrict__ embs, const float* __restrict__ weights,
        const int*   __restrict__ nbset, const float* __restrict__ Ww,
        const float* __restrict__ Wb, const float* __restrict__ hq,
        float* __restrict__ out, int N) {
    __shared__ float s_Ww[(C_DIM + H_DIM) * H_DIM];   // 32 KB
    int tid = threadIdx.x;
    const float4* w4 = (const float4*)Ww;
    float4* s4 = (float4*)s_Ww;
    for (int i = tid; i < (C_DIM + H_DIM) * H_DIM / 4; i += blockDim.x) s4[i] = w4[i];
    __syncthreads();

    int wave = tid >> 6, lane = tid & 63;
    int n = blockIdx.x * WPB + wave;
    if (n >= N) return;

    // One vector load fetches all 32 neighbor ids (lanes 32..63 duplicate),
    // one vector load fetches all 32 weights at once (no scalar-load chain).
    const int* nb_row = nbset + (size_t)n * K_NB;
    int   nb_l = nb_row[lane & (K_NB - 1)];
    const float* w_row = weights + (size_t)n * (size_t)N;
    float w_l  = w_row[nb_l];
    float e    = embs[(size_t)n * C_DIM + lane];

    float acc = 0.0f, sw = 0.0f;
    #pragma unroll
    for (int k = 0; k < K_NB; ++k) {
        int   nb = __builtin_amdgcn_readlane(nb_l, k);     // uniform SGPR base
        float w  = lane_bcast(w_l, k);                     // broadcast from vector reg
        acc = fmaf(w, hq[(size_t)nb * H_DIM + lane], acc); // coalesced 256 B row
        sw += w;
    }
    float ws = acc / (sw + 1e-6f);

    float o0 = Wb[lane], o1 = 0.0f;
    #pragma unroll
    for (int c = 0; c < C_DIM; c += 2) {
        float m0 = s_Ww[c * H_DIM + lane];
        float m1 = s_Ww[(c + 1) * H_DIM + lane];
        o0 = fmaf(lane_bcast(e, c),     m0, o0);
        o1 = fmaf(lane_bcast(e, c + 1), m1, o1);
    }
    #pragma unroll
    for (int c = 0; c < C_DIM; c += 2) {
        float m0 = s_Ww[(C_DIM + c) * H_DIM + lane];
        float m1 = s_Ww[(C_DIM + c + 1) * H_DIM + lane];
        o0 = fmaf(lane_bcast(ws, c),     m0, o0);
        o1 = fmaf(lane_bcast(ws, c + 1), m1, o1);
    }
    float o = leaky(o0 + o1);

    float sq = o * o;
    #pragma unroll
    for (int off = 32; off > 0; off >>= 1) sq += __shfl_xor(sq, off, 64);
    out[(size_t)n * H_DIM + lane] = o / (sqrtf(sq) + 1e-6f);
}

extern "C" void kernel_launch(void* const* d_in, const int* in_sizes, int n_in,
                              void* d_out, int out_size, void* d_ws, size_t ws_size,
                              hipStream_t stream) {
    const float* embs    = (const float*)d_in[0];   // (1, N, 64)
    const float* weights = (const float*)d_in[1];   // (N, N)
    const int*   nbset   = (const int*)  d_in[2];   // (N, 32)
    const float* Qw      = (const float*)d_in[3];   // (64, 64)
    const float* Qb      = (const float*)d_in[4];   // (64,)
    const float* Ww      = (const float*)d_in[5];   // (128, 64)
    const float* Wb      = (const float*)d_in[6];   // (64,)
    float* out = (float*)d_out;                     // (1, N, 64)

    const int N = in_sizes[2] / K_NB;               // 10000
    float* hq = (float*)d_ws;                       // N*64 floats = 2.56 MB

    int blocks = (N + WPB - 1) / WPB;
    stage1_kernel<<<blocks, WPB * 64, 0, stream>>>(embs, Qw, Qb, hq, N);
    stage2_kernel<<<blocks, WPB * 64, 0, stream>>>(embs, weights, nbset,
                                                   Ww, Wb, hq, out, N);
}